// Round 15
// baseline (321.280 us; speedup 1.0000x reference)
//
#include <hip/hip_runtime.h>
#include <hip/hip_bf16.h>

#define BB    8
#define NNTOK 1024
#define CCH   640
#define HH    8
#define DHD   80
#define RRW   3
#define MM    (BB * NNTOK)      // 8192
#define INNER 640
#define SCALE 0.111803398874989484820458954f  // 80^-0.5
// log2(e) folded into Q pre-scale so softmax is a bare v_exp_f32 (exp2)
#define QSCALE (SCALE * 1.44269504088896340736f)

#define KSTR 88   // attn Ks row stride (u16) — 176 B
#define VSTR 72   // attn Vt row stride (u16) — 144 B, 16B-aligned
#define ESTR 136  // proj epilogue staging stride (u16) — 272 B, 16B-aligned
#define PKST 36   // proj_qkv K-slice row stride (u16): 32 data + 4 pad

typedef __bf16 bf16x8 __attribute__((ext_vector_type(8)));
typedef float  f32x4  __attribute__((ext_vector_type(4)));

__device__ __forceinline__ unsigned short f2b(float f) {   // f32 -> bf16 bits, RNE
    union { float f; unsigned int u; } v; v.f = f;
    unsigned int r = v.u + 0x7fffu + ((v.u >> 16) & 1u);
    return (unsigned short)(r >> 16);
}
__device__ __forceinline__ bf16x8 zero8() {
    bf16x8 z;
#pragma unroll
    for (int i = 0; i < 8; i++) z[i] = (__bf16)0.0f;
    return z;
}
__device__ __forceinline__ f32x4 zero4() {
    f32x4 z;
#pragma unroll
    for (int i = 0; i < 4; i++) z[i] = 0.0f;
    return z;
}
// exp2: single v_exp_f32 (Q pre-scaled by log2e). Fallback is mathematically identical.
__device__ __forceinline__ float fexp2(float x) {
#if __has_builtin(__builtin_amdgcn_exp2f)
    return __builtin_amdgcn_exp2f(x);
#else
    return __expf(x * 0.69314718055994530942f);
#endif
}

// ---------- f32 -> bf16 cast ----------
__global__ __launch_bounds__(256) void castk(const float* __restrict__ s,
                                             unsigned short* __restrict__ d, int n) {
    int i = (blockIdx.x * 256 + threadIdx.x) * 4;
    if (i < n) {
        float4 f = *(const float4*)(s + i);
        ushort4 o;
        o.x = f2b(f.x); o.y = f2b(f.y); o.z = f2b(f.z); o.w = f2b(f.w);
        *(ushort4*)(d + i) = o;
    }
}

// ---------- 4 weight casts in one launch ----------
__global__ __launch_bounds__(256) void castw4(
    const float* __restrict__ w0, const float* __restrict__ w1,
    const float* __restrict__ w2, const float* __restrict__ w3,
    unsigned short* __restrict__ d0, unsigned short* __restrict__ d1,
    unsigned short* __restrict__ d2, unsigned short* __restrict__ d3, int n)
{
    const float* s; unsigned short* d;
    switch (blockIdx.y) {
        case 0: s = w0; d = d0; break;
        case 1: s = w1; d = d1; break;
        case 2: s = w2; d = d2; break;
        default: s = w3; d = d3; break;
    }
    int i = (blockIdx.x * 256 + threadIdx.x) * 4;
    if (i < n) {
        float4 f = *(const float4*)(s + i);
        ushort4 o;
        o.x = f2b(f.x); o.y = f2b(f.y); o.z = f2b(f.z); o.w = f2b(f.w);
        *(ushort4*)(d + i) = o;
    }
}

// ---------- QKV projection: 512 thr, 128x128 tile, PREFETCH-1 double buffer (r24) ----------
// r24 vs r22 (verified): the K-loop is restructured to attn's proven prefetch pattern
// (sync -> issue load(it+1) -> compute(it) -> write other buf). r22 exposed full
// L2/L3 latency every iteration (load -> sync -> write -> sync -> compute; every
// proj variant measured MfmaUtil 5-7%). K-step 64->32 so the dbuf fits static LDS
// (2buf x (X+W) x 128x36 u16 = 36,864 B, same footprint as r22); 20 iterations;
// held regs drop to 2 uint4/thread (proven-safe budget is 4). Summation order
// bit-identical (ascending 32-slices). Epilogue/grids unchanged.
// z=0 -> q (PRE-SCALED by log2e/sqrt(D)); z=1 -> k; z=2 -> v transposed [b,h,d,n].
__global__ __launch_bounds__(512, 4) void proj_qkv_mfma(
    const unsigned short* __restrict__ xb,
    const unsigned short* __restrict__ wqb,
    const unsigned short* __restrict__ wkb,
    const unsigned short* __restrict__ wvb,
    unsigned short* __restrict__ q16, unsigned short* __restrict__ k16,
    unsigned short* __restrict__ vto)
{
    __shared__ __align__(16) unsigned short Sh[2 * 2 * 128 * PKST];  // [buf][X|W][128][PKST]
    const int BUFO = 2 * 128 * PKST;   // 9216 u16 per buffer
    const int t = threadIdx.x;
    const int wvid = t >> 6, lane = t & 63, col = lane & 15, quad = lane >> 4;
    const int wrow = wvid & 3, wcol = wvid >> 2;
    const int m0 = blockIdx.x * 128, i0 = blockIdx.y * 128, z = blockIdx.z;
    const unsigned short* W = (z == 0) ? wqb : (z == 1) ? wkb : wvb;
    const int srow = t >> 2, sseg = t & 3;   // 512 thr cover 128 rows x 4 uint4

    f32x4 accA[4], accB[4];
#pragma unroll
    for (int nt = 0; nt < 4; nt++) { accA[nt] = zero4(); accB[nt] = zero4(); }

    // prologue: stage K-slice 0 into buffer 0
    {
        uint4 xv = *(const uint4*)(xb + (size_t)(m0 + srow) * INNER + sseg * 8);
        uint4 wv = *(const uint4*)(W  + (size_t)(i0 + srow) * INNER + sseg * 8);
        *(uint4*)&Sh[srow * PKST + sseg * 8] = xv;
        *(uint4*)&Sh[128 * PKST + srow * PKST + sseg * 8] = wv;
    }
    for (int it = 0; it < 20; it++) {   // 20 K-slices of 32
        __syncthreads();   // RAW: buf[it&1] staged (prev iter / prologue)

        // issue slice it+1 loads NOW (consumed by writes at end of this iter)
        const int ktn = ((it + 1 < 20) ? it + 1 : 19) * 32;
        uint4 xv = *(const uint4*)(xb + (size_t)(m0 + srow) * INNER + ktn + sseg * 8);
        uint4 wv = *(const uint4*)(W  + (size_t)(i0 + srow) * INNER + ktn + sseg * 8);

        const unsigned short* Xs  = Sh + (it & 1) * BUFO;
        const unsigned short* Wsh = Xs + 128 * PKST;
        bf16x8 afA = *(const bf16x8*)&Xs[(wrow * 32 + col) * PKST + quad * 8];
        bf16x8 afB = *(const bf16x8*)&Xs[(wrow * 32 + 16 + col) * PKST + quad * 8];
#pragma unroll
        for (int nt = 0; nt < 4; nt++) {
            bf16x8 bfr = *(const bf16x8*)&Wsh[(wcol * 64 + nt * 16 + col) * PKST + quad * 8];
            accA[nt] = __builtin_amdgcn_mfma_f32_16x16x32_bf16(afA, bfr, accA[nt], 0, 0, 0);
            accB[nt] = __builtin_amdgcn_mfma_f32_16x16x32_bf16(afB, bfr, accB[nt], 0, 0, 0);
        }
        // write slice it+1 into the other buffer (vmcnt waits here => full-iter
        // latency window for the prefetch, exactly the attn pattern)
        unsigned short* Xw = Sh + ((it + 1) & 1) * BUFO;
        *(uint4*)&Xw[srow * PKST + sseg * 8] = xv;
        *(uint4*)&Xw[128 * PKST + srow * PKST + sseg * 8] = wv;
    }
    // ---- coalesced-store epilogue (r19 pattern; Ts overlays Sh: 34,816 <= 36,864 B)
    __syncthreads();   // WAR: last MFMAs read Sh
    unsigned short* Ts = Sh;
    const int rA = wrow * 32 + quad * 4;
    if (z != 2) {
        const float sc = (z == 0) ? QSCALE : 1.0f;
#pragma unroll
        for (int nt = 0; nt < 4; nt++) {
            const int ci = wcol * 64 + nt * 16 + col;
#pragma unroll
            for (int r = 0; r < 4; r++) {
                Ts[(rA + r) * ESTR + ci]      = f2b(accA[nt][r] * sc);
                Ts[(rA + 16 + r) * ESTR + ci] = f2b(accB[nt][r] * sc);
            }
        }
        __syncthreads();
        unsigned short* dst = (z == 0) ? q16 : k16;
#pragma unroll
        for (int j = 0; j < 4; j++) {
            const int idx = t + 512 * j, row = idx >> 4, seg = idx & 15;
            uint4 v = *(const uint4*)&Ts[row * ESTR + seg * 8];
            *(uint4*)(dst + (size_t)(m0 + row) * INNER + i0 + seg * 8) = v;
        }
    } else {
#pragma unroll
        for (int nt = 0; nt < 4; nt++) {
            const int ci = wcol * 64 + nt * 16 + col;
#pragma unroll
            for (int r = 0; r < 4; r++) {
                Ts[ci * ESTR + rA + r]      = f2b(accA[nt][r]);
                Ts[ci * ESTR + rA + 16 + r] = f2b(accB[nt][r]);
            }
        }
        __syncthreads();
        const int bfm = m0 >> 10, n0 = m0 & (NNTOK - 1);   // 128-row tiles never straddle frames
#pragma unroll
        for (int j = 0; j < 4; j++) {
            const int idx = t + 512 * j, li = idx >> 4, seg = idx & 15;
            const int i = i0 + li;
            const int h = i / DHD, dd = i % DHD;
            uint4 v = *(const uint4*)&Ts[li * ESTR + seg * 8];
            *(uint4*)(vto + ((size_t)(bfm * HH + h) * DHD + dd) * NNTOK + n0 + seg * 8) = v;
        }
    }
}

// stored-row permutation for K staging: token tau -> LDS row s(tau).
// After SWAPPED QK^T (A=K, B=Q), lane (col,quad)'s 16 S-values are exactly
// tokens {8q+0..7, 32+8q+0..7} for qrow=col — the PV A-fragment slot order.
__device__ __forceinline__ int ksrow(int tau) {
    return (((tau >> 5) * 2 + ((tau >> 2) & 1)) << 4) + (((tau >> 3) & 3) << 2) + (tau & 3);
}

// ---------- MFMA flash attention: 32 q-rows/wave + T5 setprio (verified r21/r12) ----------
// TLP sweet spot measured: 8 waves/CU in 2 independent blocks (r16 16w/CU: 99us;
// r17 8w/CU: 86us; r23 4w/CU: 103us). Do not change the tiling ratio again.
__global__ __launch_bounds__(256, 2) void attn_mfma10(
    const unsigned short* __restrict__ qb, const unsigned short* __restrict__ kb,
    const unsigned short* __restrict__ vt, const int* __restrict__ ctx,
    unsigned short* __restrict__ ao)
{
    __shared__ __align__(16) unsigned short Ks[2][64 * KSTR];   // [stored key row][dim]
    __shared__ __align__(16) unsigned short Vt[2][DHD * VSTR];  // [dim][token]
    const int t = threadIdx.x;
    const int wvid = t >> 6, lane = t & 63, col = lane & 15, quad = lane >> 4;
    const int qt = blockIdx.x, h = blockIdx.y, b = blockIdx.z;

    // Q fragments (B operand; n=col, k=quad*8+j): set A rows wvid*32+col,
    // set B rows wvid*32+16+col.
    bf16x8 qfA0, qfA1, qfA2, qfB0, qfB1, qfB2;
    {
        const unsigned short* qpA = qb + (size_t)(b * NNTOK + qt * 128 + wvid * 32 + col) * INNER + h * DHD;
        const unsigned short* qpB = qpA + (size_t)16 * INNER;
        qfA0 = *(const bf16x8*)(qpA + quad * 8);
        qfA1 = *(const bf16x8*)(qpA + 32 + quad * 8);
        qfB0 = *(const bf16x8*)(qpB + quad * 8);
        qfB1 = *(const bf16x8*)(qpB + 32 + quad * 8);
        qfA2 = zero8(); qfB2 = zero8();
        if (quad < 2) {
            qfA2 = *(const bf16x8*)(qpA + 64 + quad * 8);
            qfB2 = *(const bf16x8*)(qpB + 64 + quad * 8);
        }
    }
    f32x4 oA[5], oB[5];
#pragma unroll
    for (int dt = 0; dt < 5; dt++) { oA[dt] = zero4(); oB[dt] = zero4(); }
    float lpA = 0.0f, lpB = 0.0f;   // per-lane partial row sums (qrow = col / 16+col)

    // staging index maps (coalesced, 256 threads):
    // K chunk = 64 tokens x 160B = 640 uint4 (rows PERMUTED via ksrow);
    // V chunk = 80 dims x 128B = 640 uint4 (linear). 640 = 256*2.5.
    const int i0 = t, i1 = t + 256, i2 = t + 512;     // i2 valid if t < 128
    const int ktok0 = i0 / 10, kseg0 = i0 % 10, ksr0 = ksrow(ktok0);
    const int ktok1 = i1 / 10, kseg1 = i1 % 10, ksr1 = ksrow(ktok1);
    const int ktok2 = i2 / 10, kseg2 = i2 % 10, ksr2 = ksrow(ktok2);
    const int vd0 = i0 >> 3, vs0 = i0 & 7;
    const int vd1 = i1 >> 3, vs1 = i1 & 7;
    const int vd2 = i2 >> 3, vs2 = i2 & 7;

    // prologue: stage chunk 0 into buffer 0
    {
        const int fr = ctx[b * RRW];
        const unsigned short* kbase = kb + (size_t)(fr * NNTOK) * INNER + h * DHD;
        const unsigned short* vbase = vt + ((size_t)(fr * HH + h) * DHD) * NNTOK;
        uint4 ka0 = *(const uint4*)(kbase + (size_t)ktok0 * INNER + kseg0 * 8);
        uint4 ka1 = *(const uint4*)(kbase + (size_t)ktok1 * INNER + kseg1 * 8);
        uint4 va0 = *(const uint4*)(vbase + (size_t)vd0 * NNTOK + vs0 * 8);
        uint4 va1 = *(const uint4*)(vbase + (size_t)vd1 * NNTOK + vs1 * 8);
        *(uint4*)&Ks[0][ksr0 * KSTR + kseg0 * 8] = ka0;
        *(uint4*)&Ks[0][ksr1 * KSTR + kseg1 * 8] = ka1;
        *(uint4*)&Vt[0][vd0 * VSTR + vs0 * 8] = va0;
        *(uint4*)&Vt[0][vd1 * VSTR + vs1 * 8] = va1;
        if (t < 128) {
            uint4 ka2 = *(const uint4*)(kbase + (size_t)ktok2 * INNER + kseg2 * 8);
            uint4 va2 = *(const uint4*)(vbase + (size_t)vd2 * NNTOK + vs2 * 8);
            *(uint4*)&Ks[0][ksr2 * KSTR + kseg2 * 8] = ka2;
            *(uint4*)&Vt[0][vd2 * VSTR + vs2 * 8] = va2;
        }
    }

    for (int kc = 0; kc < (RRW * NNTOK) / 64; kc++) {   // 48 key chunks
        __syncthreads();   // RAW: buf[kc&1] staged (end of prev iter / prologue)

        // issue chunk kc+1 staging loads NOW (consumed at end of this chunk)
        const int kcn = (kc + 1 < 48) ? kc + 1 : 47;
        const int frn = ctx[b * RRW + (kcn >> 4)];
        const int tokn = (kcn & 15) * 64;
        const unsigned short* kbase = kb + (size_t)(frn * NNTOK + tokn) * INNER + h * DHD;
        const unsigned short* vbase = vt + ((size_t)(frn * HH + h) * DHD) * NNTOK + tokn;
        uint4 ka0 = *(const uint4*)(kbase + (size_t)ktok0 * INNER + kseg0 * 8);
        uint4 ka1 = *(const uint4*)(kbase + (size_t)ktok1 * INNER + kseg1 * 8);
        uint4 va0 = *(const uint4*)(vbase + (size_t)vd0 * NNTOK + vs0 * 8);
        uint4 va1 = *(const uint4*)(vbase + (size_t)vd1 * NNTOK + vs1 * 8);
        uint4 ka2, va2;
        if (t < 128) {
            ka2 = *(const uint4*)(kbase + (size_t)ktok2 * INNER + kseg2 * 8);
            va2 = *(const uint4*)(vbase + (size_t)vd2 * NNTOK + vs2 * 8);
        }

        const unsigned short* ksr = &Ks[kc & 1][0];
        const unsigned short* vtr = &Vt[kc & 1][0];

        // S^T = (QK^T)^T via SWAPPED MFMA: A = K-frags, B = Q (two row sets share
        // every K-frag read). Lane holds S[stored row n0*16+quad*4+r][qrow].
        f32x4 sA[4], sB[4];
        __builtin_amdgcn_s_setprio(1);
#pragma unroll
        for (int n0 = 0; n0 < 4; n0++) {
            const unsigned short* kp = ksr + (n0 * 16 + col) * KSTR;
            bf16x8 k0 = *(const bf16x8*)(kp + quad * 8);
            bf16x8 k1 = *(const bf16x8*)(kp + 32 + quad * 8);
            bf16x8 k2 = zero8();
            if (quad < 2) k2 = *(const bf16x8*)(kp + 64 + quad * 8);
            f32x4 svA = zero4(), svB = zero4();
            svA = __builtin_amdgcn_mfma_f32_16x16x32_bf16(k0, qfA0, svA, 0, 0, 0);
            svB = __builtin_amdgcn_mfma_f32_16x16x32_bf16(k0, qfB0, svB, 0, 0, 0);
            svA = __builtin_amdgcn_mfma_f32_16x16x32_bf16(k1, qfA1, svA, 0, 0, 0);
            svB = __builtin_amdgcn_mfma_f32_16x16x32_bf16(k1, qfB1, svB, 0, 0, 0);
            svA = __builtin_amdgcn_mfma_f32_16x16x32_bf16(k2, qfA2, svA, 0, 0, 0);
            svB = __builtin_amdgcn_mfma_f32_16x16x32_bf16(k2, qfB2, svB, 0, 0, 0);
            sA[n0] = svA; sB[n0] = svB;
        }
        __builtin_amdgcn_s_setprio(0);
        // max-free softmax, in registers: p = exp2(s); pack into PV A-frags.
        // ksrow staging => pa0[j=(n0&1)*4+r] = token quad*8+j (n0<2), pa1 tokens 32+.
        bf16x8 paA0, paA1, paB0, paB1;
#pragma unroll
        for (int n0 = 0; n0 < 4; n0++) {
            const int j0 = (n0 & 1) * 4;
            float a0 = fexp2(sA[n0][0]), a1 = fexp2(sA[n0][1]);
            float a2 = fexp2(sA[n0][2]), a3 = fexp2(sA[n0][3]);
            lpA += (a0 + a1) + (a2 + a3);
            float b0 = fexp2(sB[n0][0]), b1 = fexp2(sB[n0][1]);
            float b2 = fexp2(sB[n0][2]), b3 = fexp2(sB[n0][3]);
            lpB += (b0 + b1) + (b2 + b3);
            if (n0 < 2) {
                paA0[j0] = (__bf16)a0; paA0[j0+1] = (__bf16)a1; paA0[j0+2] = (__bf16)a2; paA0[j0+3] = (__bf16)a3;
                paB0[j0] = (__bf16)b0; paB0[j0+1] = (__bf16)b1; paB0[j0+2] = (__bf16)b2; paB0[j0+3] = (__bf16)b3;
            } else {
                paA1[j0] = (__bf16)a0; paA1[j0+1] = (__bf16)a1; paA1[j0+2] = (__bf16)a2; paA1[j0+3] = (__bf16)a3;
                paB1[j0] = (__bf16)b0; paB1[j0+1] = (__bf16)b1; paB1[j0+2] = (__bf16)b2; paB1[j0+3] = (__bf16)b3;
            }
        }
        // O += P V ; V^T B-frags from LDS — each read feeds both row sets
        __builtin_amdgcn_s_setprio(1);
#pragma unroll
        for (int dt = 0; dt < 5; dt++) {
            const unsigned short* vp = vtr + (dt * 16 + col) * VSTR;
            bf16x8 v0 = *(const bf16x8*)(vp + quad * 8);
            bf16x8 v1 = *(const bf16x8*)(vp + 32 + quad * 8);
            oA[dt] = __builtin_amdgcn_mfma_f32_16x16x32_bf16(paA0, v0, oA[dt], 0, 0, 0);
            oB[dt] = __builtin_amdgcn_mfma_f32_16x16x32_bf16(paB0, v0, oB[dt], 0, 0, 0);
            oA[dt] = __builtin_amdgcn_mfma_f32_16x16x32_bf16(paA1, v1, oA[dt], 0, 0, 0);
            oB[dt] = __builtin_amdgcn_mfma_f32_16x16x32_bf16(paB1, v1, oB[dt], 0, 0, 0);
        }
        __builtin_amdgcn_s_setprio(0);
        // write chunk kc+1 staging into the other buffer (compiler waits vmcnt here,
        // at the END of the chunk => full-chunk latency window for the prefetch)
        {
            unsigned short* ksb = &Ks[(kc + 1) & 1][0];
            unsigned short* vtb = &Vt[(kc + 1) & 1][0];
            *(uint4*)&ksb[ksr0 * KSTR + kseg0 * 8] = ka0;
            *(uint4*)&ksb[ksr1 * KSTR + kseg1 * 8] = ka1;
            *(uint4*)&vtb[vd0 * VSTR + vs0 * 8] = va0;
            *(uint4*)&vtb[vd1 * VSTR + vs1 * 8] = va1;
            if (t < 128) {
                *(uint4*)&ksb[ksr2 * KSTR + kseg2 * 8] = ka2;
                *(uint4*)&vtb[vd2 * VSTR + vs2 * 8] = va2;
            }
        }
    }
    // final l reduction: lane holds partial for its qrow; sum across the 4 quads.
    float lsA = lpA, lsB = lpB;
    lsA += __shfl_xor(lsA, 16); lsA += __shfl_xor(lsA, 32);
    lsB += __shfl_xor(lsB, 16); lsB += __shfl_xor(lsB, 32);
    // lane now holds full l for qrow = col (A) / 16+col (B)
    float invA[4], invB[4];
#pragma unroll
    for (int r = 0; r < 4; r++) {
        invA[r] = 1.0f / __shfl(lsA, quad * 4 + r);
        invB[r] = 1.0f / __shfl(lsB, quad * 4 + r);
    }
    // epilogue: C-layout store — O rows = quad*4+r (A) / 16+quad*4+r (B)
#pragma unroll
    for (int r = 0; r < 4; r++) {
        unsigned short* opA = ao + (size_t)(b * NNTOK + qt * 128 + wvid * 32 + quad * 4 + r) * INNER + h * DHD;
        unsigned short* opB = opA + (size_t)16 * INNER;
#pragma unroll
        for (int dt = 0; dt < 5; dt++) {
            opA[dt * 16 + col] = f2b(oA[dt][r] * invA[r]);
            opB[dt * 16 + col] = f2b(oB[dt][r] * invB[r]);
        }
    }
}

// ---------- out projection, 64x64 tile, PREFETCH-1 double buffer (r24) ----------
// Same restructure as proj_qkv: K-step 64, dbuf (2 x (X+W) x 64x72 u16 = 36,864 B),
// 10 iterations, 4 uint4 held (proven-safe), 1 barrier/iter.
__global__ __launch_bounds__(256) void proj_out_mfma(
    const unsigned short* __restrict__ ab, const unsigned short* __restrict__ wob,
    const float* __restrict__ bo, float* __restrict__ out)
{
    __shared__ __align__(16) unsigned short Sh[2 * 2 * 64 * 72];   // [buf][X|W][64][72]
    const int BUFO = 2 * 64 * 72;   // 9216 u16 per buffer
    const int t = threadIdx.x;
    const int wvid = t >> 6, lane = t & 63, col = lane & 15, quad = lane >> 4;
    const int m0 = blockIdx.x * 64, i0 = blockIdx.y * 64;
    const int srow = t >> 2, sseg = t & 3;   // 256 thr cover 64 rows x (2x8=16B segs x2)

    float bias[4];
#pragma unroll
    for (int nt = 0; nt < 4; nt++) bias[nt] = bo[i0 + nt * 16 + col];

    f32x4 acc[4];
#pragma unroll
    for (int nt = 0; nt < 4; nt++) acc[nt] = zero4();

    // prologue: stage K-slice 0 into buffer 0
    {
        uint4 x0 = *(const uint4*)(ab  + (size_t)(m0 + srow) * INNER + sseg * 16);
        uint4 x1 = *(const uint4*)(ab  + (size_t)(m0 + srow) * INNER + sseg * 16 + 8);
        uint4 w0 = *(const uint4*)(wob + (size_t)(i0 + srow) * INNER + sseg * 16);
        uint4 w1 = *(const uint4*)(wob + (size_t)(i0 + srow) * INNER + sseg * 16 + 8);
        *(uint4*)&Sh[srow * 72 + sseg * 16]               = x0;
        *(uint4*)&Sh[srow * 72 + sseg * 16 + 8]           = x1;
        *(uint4*)&Sh[64 * 72 + srow * 72 + sseg * 16]     = w0;
        *(uint4*)&Sh[64 * 72 + srow * 72 + sseg * 16 + 8] = w1;
    }
    for (int it = 0; it < 10; it++) {   // 10 K-slices of 64
        __syncthreads();   // RAW: buf[it&1] staged

        const int ktn = ((it + 1 < 10) ? it + 1 : 9) * 64;
        uint4 x0 = *(const uint4*)(ab  + (size_t)(m0 + srow) * INNER + ktn + sseg * 16);
        uint4 x1 = *(const uint4*)(ab  + (size_t)(m0 + srow) * INNER + ktn + sseg * 16 + 8);
        uint4 w0 = *(const uint4*)(wob + (size_t)(i0 + srow) * INNER + ktn + sseg * 16);
        uint4 w1 = *(const uint4*)(wob + (size_t)(i0 + srow) * INNER + ktn + sseg * 16 + 8);

        const unsigned short* Xs  = Sh + (it & 1) * BUFO;
        const unsigned short* Wsh = Xs + 64 * 72;
#pragma unroll
        for (int kbk = 0; kbk < 2; kbk++) {
            bf16x8 af = *(const bf16x8*)&Xs[(wvid * 16 + col) * 72 + kbk * 32 + quad * 8];
#pragma unroll
            for (int nt = 0; nt < 4; nt++) {
                bf16x8 bfr = *(const bf16x8*)&Wsh[(nt * 16 + col) * 72 + kbk * 32 + quad * 8];
                acc[nt] = __builtin_amdgcn_mfma_f32_16x16x32_bf16(af, bfr, acc[nt], 0, 0, 0);
            }
        }
        unsigned short* Xw = Sh + ((it + 1) & 1) * BUFO;
        *(uint4*)&Xw[srow * 72 + sseg * 16]               = x0;
        *(uint4*)&Xw[srow * 72 + sseg * 16 + 8]           = x1;
        *(uint4*)&Xw[64 * 72 + srow * 72 + sseg * 16]     = w0;
        *(uint4*)&Xw[64 * 72 + srow * 72 + sseg * 16 + 8] = w1;
    }
#pragma unroll
    for (int nt = 0; nt < 4; nt++)
#pragma unroll
        for (int r = 0; r < 4; r++)
            out[(size_t)(m0 + wvid * 16 + quad * 4 + r) * CCH + i0 + nt * 16 + col] = acc[nt][r] + bias[nt];
}

extern "C" void kernel_launch(void* const* d_in, const int* in_sizes, int n_in,
                              void* d_out, int out_size, void* d_ws, size_t ws_size,
                              hipStream_t stream) {
    const float* x  = (const float*)d_in[0];
    const float* wq = (const float*)d_in[1];
    const float* wk = (const float*)d_in[2];
    const float* wv = (const float*)d_in[3];
    const float* wo = (const float*)d_in[4];
    const float* bo = (const float*)d_in[5];
    const int* ctx  = (const int*)d_in[6];
    float* out = (float*)d_out;

    const size_t XN = (size_t)MM * INNER;     // 5,242,880
    const size_t WN = (size_t)INNER * CCH;    //   409,600
    unsigned short* q16 = (unsigned short*)d_ws;            // bf16 (pre-scaled by log2e/sqrt(D))
    unsigned short* k16 = q16 + XN;
    unsigned short* vto = k16 + XN;                         // bf16 [b,h,d,n]
    unsigned short* xb  = vto + XN;                         // dead after proj
    unsigned short* aob = xb;                               // alias: attn output bf16
    unsigned short* wqb = xb + XN;
    unsigned short* wkb = wqb + WN;
    unsigned short* wvb = wkb + WN;
    unsigned short* wob = wvb + WN;                         // total ~45 MB (proven budget)

    castk<<<dim3((XN / 4 + 255) / 256), 256, 0, stream>>>(x, xb, (int)XN);
    castw4<<<dim3((WN / 4 + 255) / 256, 4), 256, 0, stream>>>(wq, wk, wv, wo, wqb, wkb, wvb, wob, (int)WN);

    proj_qkv_mfma<<<dim3(MM / 128, INNER / 128, 3), 512, 0, stream>>>(xb, wqb, wkb, wvb, q16, k16, vto);
    attn_mfma10<<<dim3(NNTOK / 128, HH, BB), 256, 0, stream>>>(q16, k16, vto, ctx, aob);
    proj_out_mfma<<<dim3(MM / 64, CCH / 64), 256, 0, stream>>>(aob, wob, bo, out);
}

// Round 16
// 206.749 us; speedup vs baseline: 1.5540x; 1.5540x over previous
//
#include <hip/hip_runtime.h>
#include <hip/hip_bf16.h>

#define BB    8
#define NNTOK 1024
#define CCH   640
#define HH    8
#define DHD   80
#define RRW   3
#define MM    (BB * NNTOK)      // 8192
#define INNER 640
#define SCALE 0.111803398874989484820458954f  // 80^-0.5
// log2(e) folded into Q pre-scale so softmax is a bare v_exp_f32 (exp2)
#define QSCALE (SCALE * 1.44269504088896340736f)

#define KSTR 88   // attn Ks row stride (u16) — 176 B
#define VSTR 72   // attn Vt row stride (u16) — 144 B, 16B-aligned
#define ESTR 136  // proj epilogue staging stride (u16) — 272 B, 16B-aligned

typedef __bf16 bf16x8 __attribute__((ext_vector_type(8)));
typedef float  f32x4  __attribute__((ext_vector_type(4)));

__device__ __forceinline__ unsigned short f2b(float f) {   // f32 -> bf16 bits, RNE
    union { float f; unsigned int u; } v; v.f = f;
    unsigned int r = v.u + 0x7fffu + ((v.u >> 16) & 1u);
    return (unsigned short)(r >> 16);
}
__device__ __forceinline__ bf16x8 zero8() {
    bf16x8 z;
#pragma unroll
    for (int i = 0; i < 8; i++) z[i] = (__bf16)0.0f;
    return z;
}
__device__ __forceinline__ f32x4 zero4() {
    f32x4 z;
#pragma unroll
    for (int i = 0; i < 4; i++) z[i] = 0.0f;
    return z;
}
// exp2: single v_exp_f32 (Q pre-scaled by log2e). Fallback is mathematically identical.
__device__ __forceinline__ float fexp2(float x) {
#if __has_builtin(__builtin_amdgcn_exp2f)
    return __builtin_amdgcn_exp2f(x);
#else
    return __expf(x * 0.69314718055994530942f);
#endif
}

// ---------- f32 -> bf16 cast ----------
__global__ __launch_bounds__(256) void castk(const float* __restrict__ s,
                                             unsigned short* __restrict__ d, int n) {
    int i = (blockIdx.x * 256 + threadIdx.x) * 4;
    if (i < n) {
        float4 f = *(const float4*)(s + i);
        ushort4 o;
        o.x = f2b(f.x); o.y = f2b(f.y); o.z = f2b(f.z); o.w = f2b(f.w);
        *(ushort4*)(d + i) = o;
    }
}

// ---------- 4 weight casts in one launch ----------
__global__ __launch_bounds__(256) void castw4(
    const float* __restrict__ w0, const float* __restrict__ w1,
    const float* __restrict__ w2, const float* __restrict__ w3,
    unsigned short* __restrict__ d0, unsigned short* __restrict__ d1,
    unsigned short* __restrict__ d2, unsigned short* __restrict__ d3, int n)
{
    const float* s; unsigned short* d;
    switch (blockIdx.y) {
        case 0: s = w0; d = d0; break;
        case 1: s = w1; d = d1; break;
        case 2: s = w2; d = d2; break;
        default: s = w3; d = d3; break;
    }
    int i = (blockIdx.x * 256 + threadIdx.x) * 4;
    if (i < n) {
        float4 f = *(const float4*)(s + i);
        ushort4 o;
        o.x = f2b(f.x); o.y = f2b(f.y); o.z = f2b(f.z); o.w = f2b(f.w);
        *(ushort4*)(d + i) = o;
    }
}

// ---------- QKV projection, 512 threads, 128x128 tile, 4x2 wave grid (r22-verified) ----------
// Holds EXACTLY 4 uint4 across the barrier (16 VGPR, proven-safe). NOTE: prefetch-1
// dbuf variant (r24) regressed 2x — per-barrier compute (~8 MFMA) is far shorter than
// the prefetch latency, so every iteration ate a full L2 round-trip. This 2-barrier
// form is the measured optimum of 4 proj structures tried (r7, r20, r22, r24).
// z=0 -> q (PRE-SCALED by log2e/sqrt(D)); z=1 -> k; z=2 -> v transposed [b,h,d,n].
__global__ __launch_bounds__(512, 4) void proj_qkv_mfma(
    const unsigned short* __restrict__ xb,
    const unsigned short* __restrict__ wqb,
    const unsigned short* __restrict__ wkb,
    const unsigned short* __restrict__ wvb,
    unsigned short* __restrict__ q16, unsigned short* __restrict__ k16,
    unsigned short* __restrict__ vto)
{
    __shared__ __align__(16) unsigned short Sh[2 * 128 * 72];   // Xs | Wsh; epilogue Ts overlay
    unsigned short* Xs  = Sh;
    unsigned short* Wsh = Sh + 128 * 72;
    const int t = threadIdx.x;
    const int wvid = t >> 6, lane = t & 63, col = lane & 15, quad = lane >> 4;
    const int wrow = wvid & 3, wcol = wvid >> 2;
    const int m0 = blockIdx.x * 128, i0 = blockIdx.y * 128, z = blockIdx.z;
    const unsigned short* W = (z == 0) ? wqb : (z == 1) ? wkb : wvb;
    const int srow = t >> 3, sseg = t & 7;   // staging: rows srow & 64+srow, seg sseg

    f32x4 accA[4], accB[4];
#pragma unroll
    for (int nt = 0; nt < 4; nt++) { accA[nt] = zero4(); accB[nt] = zero4(); }

    for (int kt = 0; kt < INNER; kt += 64) {
        // exactly 4 uint4 held across the barrier (16 VGPR — proven-safe budget)
        uint4 x0 = *(const uint4*)(xb + (size_t)(m0 + srow) * INNER + kt + sseg * 8);
        uint4 x1 = *(const uint4*)(xb + (size_t)(m0 + 64 + srow) * INNER + kt + sseg * 8);
        uint4 w0 = *(const uint4*)(W  + (size_t)(i0 + srow) * INNER + kt + sseg * 8);
        uint4 w1 = *(const uint4*)(W  + (size_t)(i0 + 64 + srow) * INNER + kt + sseg * 8);
        __syncthreads();
        *(uint4*)&Xs[srow * 72 + sseg * 8]        = x0;
        *(uint4*)&Xs[(64 + srow) * 72 + sseg * 8] = x1;
        *(uint4*)&Wsh[srow * 72 + sseg * 8]        = w0;
        *(uint4*)&Wsh[(64 + srow) * 72 + sseg * 8] = w1;
        __syncthreads();
#pragma unroll
        for (int kbk = 0; kbk < 2; kbk++) {
            bf16x8 afA = *(const bf16x8*)&Xs[(wrow * 32 + col) * 72 + kbk * 32 + quad * 8];
            bf16x8 afB = *(const bf16x8*)&Xs[(wrow * 32 + 16 + col) * 72 + kbk * 32 + quad * 8];
#pragma unroll
            for (int nt = 0; nt < 4; nt++) {
                bf16x8 bfr = *(const bf16x8*)&Wsh[(wcol * 64 + nt * 16 + col) * 72 + kbk * 32 + quad * 8];
                accA[nt] = __builtin_amdgcn_mfma_f32_16x16x32_bf16(afA, bfr, accA[nt], 0, 0, 0);
                accB[nt] = __builtin_amdgcn_mfma_f32_16x16x32_bf16(afB, bfr, accB[nt], 0, 0, 0);
            }
        }
    }
    // ---- coalesced-store epilogue (r19 pattern; Ts overlays Sh) ----
    __syncthreads();   // WAR: last MFMAs read Xs/Wsh
    unsigned short* Ts = Sh;
    const int rA = wrow * 32 + quad * 4;
    if (z != 2) {
        const float sc = (z == 0) ? QSCALE : 1.0f;
#pragma unroll
        for (int nt = 0; nt < 4; nt++) {
            const int ci = wcol * 64 + nt * 16 + col;
#pragma unroll
            for (int r = 0; r < 4; r++) {
                Ts[(rA + r) * ESTR + ci]      = f2b(accA[nt][r] * sc);
                Ts[(rA + 16 + r) * ESTR + ci] = f2b(accB[nt][r] * sc);
            }
        }
        __syncthreads();
        unsigned short* dst = (z == 0) ? q16 : k16;
#pragma unroll
        for (int j = 0; j < 4; j++) {
            const int idx = t + 512 * j, row = idx >> 4, seg = idx & 15;
            uint4 v = *(const uint4*)&Ts[row * ESTR + seg * 8];
            *(uint4*)(dst + (size_t)(m0 + row) * INNER + i0 + seg * 8) = v;
        }
    } else {
#pragma unroll
        for (int nt = 0; nt < 4; nt++) {
            const int ci = wcol * 64 + nt * 16 + col;
#pragma unroll
            for (int r = 0; r < 4; r++) {
                Ts[ci * ESTR + rA + r]      = f2b(accA[nt][r]);
                Ts[ci * ESTR + rA + 16 + r] = f2b(accB[nt][r]);
            }
        }
        __syncthreads();
        const int bfm = m0 >> 10, n0 = m0 & (NNTOK - 1);   // 128-row tiles never straddle frames
#pragma unroll
        for (int j = 0; j < 4; j++) {
            const int idx = t + 512 * j, li = idx >> 4, seg = idx & 15;
            const int i = i0 + li;
            const int h = i / DHD, dd = i % DHD;
            uint4 v = *(const uint4*)&Ts[li * ESTR + seg * 8];
            *(uint4*)(vto + ((size_t)(bfm * HH + h) * DHD + dd) * NNTOK + n0 + seg * 8) = v;
        }
    }
}

// stored-row permutation for K staging: token tau -> LDS row s(tau).
// After SWAPPED QK^T (A=K, B=Q), lane (col,quad)'s 16 S-values are exactly
// tokens {8q+0..7, 32+8q+0..7} for qrow=col — the PV A-fragment slot order.
__device__ __forceinline__ int ksrow(int tau) {
    return (((tau >> 5) * 2 + ((tau >> 2) & 1)) << 4) + (((tau >> 3) & 3) << 2) + (tau & 3);
}

// ---------- MFMA flash attention: 32 q-rows/wave + T5 setprio (r21/r12-verified) ----------
// r25 change: XCD-locality grid relabel ONLY. Old grid (qt,h,b) round-robins the
// 8 qt-blocks sharing the same K/V frames onto 8 different XCDs (XCD = id%8 = qt)
// -> each XCD L2 fetches its own K/V copy; measured FETCH 128 MB vs 31.5 logical.
// New launch is (h, qt, b): XCD = id%8 = h, so all qt-blocks of one (h,b) share
// one XCD's L2. Pure blockIdx relabel — same block set, zero correctness risk.
__global__ __launch_bounds__(256, 2) void attn_mfma10(
    const unsigned short* __restrict__ qb, const unsigned short* __restrict__ kb,
    const unsigned short* __restrict__ vt, const int* __restrict__ ctx,
    unsigned short* __restrict__ ao)
{
    __shared__ __align__(16) unsigned short Ks[2][64 * KSTR];   // [stored key row][dim]
    __shared__ __align__(16) unsigned short Vt[2][DHD * VSTR];  // [dim][token]
    const int t = threadIdx.x;
    const int wvid = t >> 6, lane = t & 63, col = lane & 15, quad = lane >> 4;
    const int h = blockIdx.x, qt = blockIdx.y, b = blockIdx.z;   // r25: swapped roles

    // Q fragments (B operand; n=col, k=quad*8+j): set A rows wvid*32+col,
    // set B rows wvid*32+16+col.
    bf16x8 qfA0, qfA1, qfA2, qfB0, qfB1, qfB2;
    {
        const unsigned short* qpA = qb + (size_t)(b * NNTOK + qt * 128 + wvid * 32 + col) * INNER + h * DHD;
        const unsigned short* qpB = qpA + (size_t)16 * INNER;
        qfA0 = *(const bf16x8*)(qpA + quad * 8);
        qfA1 = *(const bf16x8*)(qpA + 32 + quad * 8);
        qfB0 = *(const bf16x8*)(qpB + quad * 8);
        qfB1 = *(const bf16x8*)(qpB + 32 + quad * 8);
        qfA2 = zero8(); qfB2 = zero8();
        if (quad < 2) {
            qfA2 = *(const bf16x8*)(qpA + 64 + quad * 8);
            qfB2 = *(const bf16x8*)(qpB + 64 + quad * 8);
        }
    }
    f32x4 oA[5], oB[5];
#pragma unroll
    for (int dt = 0; dt < 5; dt++) { oA[dt] = zero4(); oB[dt] = zero4(); }
    float lpA = 0.0f, lpB = 0.0f;   // per-lane partial row sums (qrow = col / 16+col)

    // staging index maps (coalesced, 256 threads):
    // K chunk = 64 tokens x 160B = 640 uint4 (rows PERMUTED via ksrow);
    // V chunk = 80 dims x 128B = 640 uint4 (linear). 640 = 256*2.5.
    const int i0 = t, i1 = t + 256, i2 = t + 512;     // i2 valid if t < 128
    const int ktok0 = i0 / 10, kseg0 = i0 % 10, ksr0 = ksrow(ktok0);
    const int ktok1 = i1 / 10, kseg1 = i1 % 10, ksr1 = ksrow(ktok1);
    const int ktok2 = i2 / 10, kseg2 = i2 % 10, ksr2 = ksrow(ktok2);
    const int vd0 = i0 >> 3, vs0 = i0 & 7;
    const int vd1 = i1 >> 3, vs1 = i1 & 7;
    const int vd2 = i2 >> 3, vs2 = i2 & 7;

    // prologue: stage chunk 0 into buffer 0
    {
        const int fr = ctx[b * RRW];
        const unsigned short* kbase = kb + (size_t)(fr * NNTOK) * INNER + h * DHD;
        const unsigned short* vbase = vt + ((size_t)(fr * HH + h) * DHD) * NNTOK;
        uint4 ka0 = *(const uint4*)(kbase + (size_t)ktok0 * INNER + kseg0 * 8);
        uint4 ka1 = *(const uint4*)(kbase + (size_t)ktok1 * INNER + kseg1 * 8);
        uint4 va0 = *(const uint4*)(vbase + (size_t)vd0 * NNTOK + vs0 * 8);
        uint4 va1 = *(const uint4*)(vbase + (size_t)vd1 * NNTOK + vs1 * 8);
        *(uint4*)&Ks[0][ksr0 * KSTR + kseg0 * 8] = ka0;
        *(uint4*)&Ks[0][ksr1 * KSTR + kseg1 * 8] = ka1;
        *(uint4*)&Vt[0][vd0 * VSTR + vs0 * 8] = va0;
        *(uint4*)&Vt[0][vd1 * VSTR + vs1 * 8] = va1;
        if (t < 128) {
            uint4 ka2 = *(const uint4*)(kbase + (size_t)ktok2 * INNER + kseg2 * 8);
            uint4 va2 = *(const uint4*)(vbase + (size_t)vd2 * NNTOK + vs2 * 8);
            *(uint4*)&Ks[0][ksr2 * KSTR + kseg2 * 8] = ka2;
            *(uint4*)&Vt[0][vd2 * VSTR + vs2 * 8] = va2;
        }
    }

    for (int kc = 0; kc < (RRW * NNTOK) / 64; kc++) {   // 48 key chunks
        __syncthreads();   // RAW: buf[kc&1] staged (end of prev iter / prologue)

        // issue chunk kc+1 staging loads NOW (consumed at end of this chunk)
        const int kcn = (kc + 1 < 48) ? kc + 1 : 47;
        const int frn = ctx[b * RRW + (kcn >> 4)];
        const int tokn = (kcn & 15) * 64;
        const unsigned short* kbase = kb + (size_t)(frn * NNTOK + tokn) * INNER + h * DHD;
        const unsigned short* vbase = vt + ((size_t)(frn * HH + h) * DHD) * NNTOK + tokn;
        uint4 ka0 = *(const uint4*)(kbase + (size_t)ktok0 * INNER + kseg0 * 8);
        uint4 ka1 = *(const uint4*)(kbase + (size_t)ktok1 * INNER + kseg1 * 8);
        uint4 va0 = *(const uint4*)(vbase + (size_t)vd0 * NNTOK + vs0 * 8);
        uint4 va1 = *(const uint4*)(vbase + (size_t)vd1 * NNTOK + vs1 * 8);
        uint4 ka2, va2;
        if (t < 128) {
            ka2 = *(const uint4*)(kbase + (size_t)ktok2 * INNER + kseg2 * 8);
            va2 = *(const uint4*)(vbase + (size_t)vd2 * NNTOK + vs2 * 8);
        }

        const unsigned short* ksr = &Ks[kc & 1][0];
        const unsigned short* vtr = &Vt[kc & 1][0];

        // S^T = (QK^T)^T via SWAPPED MFMA: A = K-frags, B = Q (two row sets share
        // every K-frag read). Lane holds S[stored row n0*16+quad*4+r][qrow].
        f32x4 sA[4], sB[4];
        __builtin_amdgcn_s_setprio(1);
#pragma unroll
        for (int n0 = 0; n0 < 4; n0++) {
            const unsigned short* kp = ksr + (n0 * 16 + col) * KSTR;
            bf16x8 k0 = *(const bf16x8*)(kp + quad * 8);
            bf16x8 k1 = *(const bf16x8*)(kp + 32 + quad * 8);
            bf16x8 k2 = zero8();
            if (quad < 2) k2 = *(const bf16x8*)(kp + 64 + quad * 8);
            f32x4 svA = zero4(), svB = zero4();
            svA = __builtin_amdgcn_mfma_f32_16x16x32_bf16(k0, qfA0, svA, 0, 0, 0);
            svB = __builtin_amdgcn_mfma_f32_16x16x32_bf16(k0, qfB0, svB, 0, 0, 0);
            svA = __builtin_amdgcn_mfma_f32_16x16x32_bf16(k1, qfA1, svA, 0, 0, 0);
            svB = __builtin_amdgcn_mfma_f32_16x16x32_bf16(k1, qfB1, svB, 0, 0, 0);
            svA = __builtin_amdgcn_mfma_f32_16x16x32_bf16(k2, qfA2, svA, 0, 0, 0);
            svB = __builtin_amdgcn_mfma_f32_16x16x32_bf16(k2, qfB2, svB, 0, 0, 0);
            sA[n0] = svA; sB[n0] = svB;
        }
        __builtin_amdgcn_s_setprio(0);
        // max-free softmax, in registers: p = exp2(s); pack into PV A-frags.
        // ksrow staging => pa0[j=(n0&1)*4+r] = token quad*8+j (n0<2), pa1 tokens 32+.
        bf16x8 paA0, paA1, paB0, paB1;
#pragma unroll
        for (int n0 = 0; n0 < 4; n0++) {
            const int j0 = (n0 & 1) * 4;
            float a0 = fexp2(sA[n0][0]), a1 = fexp2(sA[n0][1]);
            float a2 = fexp2(sA[n0][2]), a3 = fexp2(sA[n0][3]);
            lpA += (a0 + a1) + (a2 + a3);
            float b0 = fexp2(sB[n0][0]), b1 = fexp2(sB[n0][1]);
            float b2 = fexp2(sB[n0][2]), b3 = fexp2(sB[n0][3]);
            lpB += (b0 + b1) + (b2 + b3);
            if (n0 < 2) {
                paA0[j0] = (__bf16)a0; paA0[j0+1] = (__bf16)a1; paA0[j0+2] = (__bf16)a2; paA0[j0+3] = (__bf16)a3;
                paB0[j0] = (__bf16)b0; paB0[j0+1] = (__bf16)b1; paB0[j0+2] = (__bf16)b2; paB0[j0+3] = (__bf16)b3;
            } else {
                paA1[j0] = (__bf16)a0; paA1[j0+1] = (__bf16)a1; paA1[j0+2] = (__bf16)a2; paA1[j0+3] = (__bf16)a3;
                paB1[j0] = (__bf16)b0; paB1[j0+1] = (__bf16)b1; paB1[j0+2] = (__bf16)b2; paB1[j0+3] = (__bf16)b3;
            }
        }
        // O += P V ; V^T B-frags from LDS — each read feeds both row sets
        __builtin_amdgcn_s_setprio(1);
#pragma unroll
        for (int dt = 0; dt < 5; dt++) {
            const unsigned short* vp = vtr + (dt * 16 + col) * VSTR;
            bf16x8 v0 = *(const bf16x8*)(vp + quad * 8);
            bf16x8 v1 = *(const bf16x8*)(vp + 32 + quad * 8);
            oA[dt] = __builtin_amdgcn_mfma_f32_16x16x32_bf16(paA0, v0, oA[dt], 0, 0, 0);
            oB[dt] = __builtin_amdgcn_mfma_f32_16x16x32_bf16(paB0, v0, oB[dt], 0, 0, 0);
            oA[dt] = __builtin_amdgcn_mfma_f32_16x16x32_bf16(paA1, v1, oA[dt], 0, 0, 0);
            oB[dt] = __builtin_amdgcn_mfma_f32_16x16x32_bf16(paB1, v1, oB[dt], 0, 0, 0);
        }
        __builtin_amdgcn_s_setprio(0);
        // write chunk kc+1 staging into the other buffer (compiler waits vmcnt here,
        // at the END of the chunk => full-chunk latency window for the prefetch)
        {
            unsigned short* ksb = &Ks[(kc + 1) & 1][0];
            unsigned short* vtb = &Vt[(kc + 1) & 1][0];
            *(uint4*)&ksb[ksr0 * KSTR + kseg0 * 8] = ka0;
            *(uint4*)&ksb[ksr1 * KSTR + kseg1 * 8] = ka1;
            *(uint4*)&vtb[vd0 * VSTR + vs0 * 8] = va0;
            *(uint4*)&vtb[vd1 * VSTR + vs1 * 8] = va1;
            if (t < 128) {
                *(uint4*)&ksb[ksr2 * KSTR + kseg2 * 8] = ka2;
                *(uint4*)&vtb[vd2 * VSTR + vs2 * 8] = va2;
            }
        }
    }
    // final l reduction: lane holds partial for its qrow; sum across the 4 quads.
    float lsA = lpA, lsB = lpB;
    lsA += __shfl_xor(lsA, 16); lsA += __shfl_xor(lsA, 32);
    lsB += __shfl_xor(lsB, 16); lsB += __shfl_xor(lsB, 32);
    // lane now holds full l for qrow = col (A) / 16+col (B)
    float invA[4], invB[4];
#pragma unroll
    for (int r = 0; r < 4; r++) {
        invA[r] = 1.0f / __shfl(lsA, quad * 4 + r);
        invB[r] = 1.0f / __shfl(lsB, quad * 4 + r);
    }
    // epilogue: C-layout store — O rows = quad*4+r (A) / 16+quad*4+r (B)
#pragma unroll
    for (int r = 0; r < 4; r++) {
        unsigned short* opA = ao + (size_t)(b * NNTOK + qt * 128 + wvid * 32 + quad * 4 + r) * INNER + h * DHD;
        unsigned short* opB = opA + (size_t)16 * INNER;
#pragma unroll
        for (int dt = 0; dt < 5; dt++) {
            opA[dt * 16 + col] = f2b(oA[dt][r] * invA[r]);
            opB[dt * 16 + col] = f2b(oB[dt][r] * invB[r]);
        }
    }
}

// ---------- out projection, bf16 MFMA, f32 output + bias (r6-proven, 64x64) ----------
__global__ __launch_bounds__(256) void proj_out_mfma(
    const unsigned short* __restrict__ ab, const unsigned short* __restrict__ wob,
    const float* __restrict__ bo, float* __restrict__ out)
{
    __shared__ __align__(16) unsigned short Xs[64 * 72];
    __shared__ __align__(16) unsigned short Wsh[64 * 72];
    const int t = threadIdx.x;
    const int wvid = t >> 6, lane = t & 63, col = lane & 15, quad = lane >> 4;
    const int m0 = blockIdx.x * 64, i0 = blockIdx.y * 64;
    const int row = t >> 2, seg = t & 3;

    float bias[4];
#pragma unroll
    for (int nt = 0; nt < 4; nt++) bias[nt] = bo[i0 + nt * 16 + col];

    f32x4 acc[4];
#pragma unroll
    for (int nt = 0; nt < 4; nt++) acc[nt] = zero4();

    for (int kt = 0; kt < INNER; kt += 64) {
        uint4 x0 = *(const uint4*)(ab  + (size_t)(m0 + row) * INNER + kt + seg * 16);
        uint4 x1 = *(const uint4*)(ab  + (size_t)(m0 + row) * INNER + kt + seg * 16 + 8);
        uint4 w0 = *(const uint4*)(wob + (size_t)(i0 + row) * INNER + kt + seg * 16);
        uint4 w1 = *(const uint4*)(wob + (size_t)(i0 + row) * INNER + kt + seg * 16 + 8);
        __syncthreads();
        *(uint4*)&Xs[row * 72 + seg * 16]      = x0;
        *(uint4*)&Xs[row * 72 + seg * 16 + 8]  = x1;
        *(uint4*)&Wsh[row * 72 + seg * 16]     = w0;
        *(uint4*)&Wsh[row * 72 + seg * 16 + 8] = w1;
        __syncthreads();
#pragma unroll
        for (int kbk = 0; kbk < 2; kbk++) {
            bf16x8 af = *(const bf16x8*)&Xs[(wvid * 16 + col) * 72 + kbk * 32 + quad * 8];
#pragma unroll
            for (int nt = 0; nt < 4; nt++) {
                bf16x8 bfr = *(const bf16x8*)&Wsh[(nt * 16 + col) * 72 + kbk * 32 + quad * 8];
                acc[nt] = __builtin_amdgcn_mfma_f32_16x16x32_bf16(af, bfr, acc[nt], 0, 0, 0);
            }
        }
    }
#pragma unroll
    for (int nt = 0; nt < 4; nt++)
#pragma unroll
        for (int r = 0; r < 4; r++)
            out[(size_t)(m0 + wvid * 16 + quad * 4 + r) * CCH + i0 + nt * 16 + col] = acc[nt][r] + bias[nt];
}

extern "C" void kernel_launch(void* const* d_in, const int* in_sizes, int n_in,
                              void* d_out, int out_size, void* d_ws, size_t ws_size,
                              hipStream_t stream) {
    const float* x  = (const float*)d_in[0];
    const float* wq = (const float*)d_in[1];
    const float* wk = (const float*)d_in[2];
    const float* wv = (const float*)d_in[3];
    const float* wo = (const float*)d_in[4];
    const float* bo = (const float*)d_in[5];
    const int* ctx  = (const int*)d_in[6];
    float* out = (float*)d_out;

    const size_t XN = (size_t)MM * INNER;     // 5,242,880
    const size_t WN = (size_t)INNER * CCH;    //   409,600
    unsigned short* q16 = (unsigned short*)d_ws;            // bf16 (pre-scaled by log2e/sqrt(D))
    unsigned short* k16 = q16 + XN;
    unsigned short* vto = k16 + XN;                         // bf16 [b,h,d,n]
    unsigned short* xb  = vto + XN;                         // dead after proj
    unsigned short* aob = xb;                               // alias: attn output bf16
    unsigned short* wqb = xb + XN;
    unsigned short* wkb = wqb + WN;
    unsigned short* wvb = wkb + WN;
    unsigned short* wob = wvb + WN;                         // total ~45 MB (proven budget)

    castk<<<dim3((XN / 4 + 255) / 256), 256, 0, stream>>>(x, xb, (int)XN);
    castw4<<<dim3((WN / 4 + 255) / 256, 4), 256, 0, stream>>>(wq, wk, wv, wo, wqb, wkb, wvb, wob, (int)WN);

    proj_qkv_mfma<<<dim3(MM / 128, INNER / 128, 3), 512, 0, stream>>>(xb, wqb, wkb, wvb, q16, k16, vto);
    attn_mfma10<<<dim3(HH, NNTOK / 128, BB), 256, 0, stream>>>(q16, k16, vto, ctx, aob);
    proj_out_mfma<<<dim3(MM / 64, CCH / 64), 256, 0, stream>>>(aob, wob, bo, out);
}